// Round 9
// baseline (181.770 us; speedup 1.0000x reference)
//
#include <hip/hip_runtime.h>
#include <hip/hip_bf16.h>

// Problem: B=2, T=2048, D=1024, H=16, HD=64.
// Runtime-detect fp32 vs bf16 inputs (inline, per-wave); canonicalize to bf16.
// convert_all -> qkv gemm (128x128, global_load_lds staging m97-style;
// Q,K:[B,H,T,64] via LDS-transpose epilogue; V:[B,H,64,T]; Q PRE-SCALED by
// log2(e)/sqrt(64)) -> SINGLE-PASS flash attention (grid (32 bh, 16 qt),
// qt = (y<8)?15-y:y-8; 32x32 MFMA, swapped QK^T, K/V staged via
// global_load_lds into a 3-BUFFER LDS RING with COUNTED vmcnt (T4: never
// vmcnt(0) in the loop) + raw s_barrier -- DMA has ~2 tiles of lead and is
// never drained; P = exp2(S), in-register pack via cvt_pk_bf16 +
// permlane32_swap, MFMA ones-row l, setprio, in-epilogue 1/l normalize +
// direct [B,T,H,64] store) -> out gemm (64x128).
// [R8 resubmission: prior round failed on GPU acquisition, never measured.]

#define TB 2
#define TT 2048
#define TD 1024
#define TH 16
#define TM (TB * TT) // 4096

#define NEG_BIG (-1e30f)
#define SCALE_LOG2 0.18033688f  // (1/sqrt(64)) * log2(e), folded into Q
#define BF16_ONE ((short)0x3F80)

typedef __attribute__((ext_vector_type(8))) short short8;
typedef __attribute__((ext_vector_type(4))) float f32x4;
typedef __attribute__((ext_vector_type(16))) float f32x16;
typedef __attribute__((ext_vector_type(4))) unsigned short ushort4v;
typedef __attribute__((ext_vector_type(4))) unsigned int u32x4;

__device__ __forceinline__ short f2bf(float f) {
    __hip_bfloat16 h = __float2bfloat16(f);
    return __builtin_bit_cast(short, h);
}

__device__ __forceinline__ float bf2f(short u) {
    unsigned int x = ((unsigned int)(unsigned short)u) << 16;
    return __builtin_bit_cast(float, x);
}

__device__ __forceinline__ float fast_exp2(float x) {
#if __has_builtin(__builtin_amdgcn_exp2f)
    return __builtin_amdgcn_exp2f(x);
#else
    return exp2f(x);
#endif
}

__device__ __forceinline__ f32x16 zero16() {
    f32x16 v;
    #pragma unroll
    for (int i = 0; i < 16; ++i) v[i] = 0.f;
    return v;
}

// Async global->LDS DMA, 16 B/lane. LDS dest is wave-uniform base + lane*16;
// global src is per-lane (pre-swizzled). Completion counted by vmcnt.
__device__ __forceinline__ void gload_lds16(const short* g, short* l) {
    __builtin_amdgcn_global_load_lds(
        (const __attribute__((address_space(1))) unsigned int*)g,
        (__attribute__((address_space(3))) unsigned int*)l,
        16, 0, 0);
}

// Inline dtype detect: sample even u16s of x; uniform per wave.
__device__ __forceinline__ int detect_bf16(const unsigned short* xq) {
    int lane = threadIdx.x & 63;
    unsigned short u = xq[lane * 2];
    int e = (u >> 7) & 0xFF;
    int sane = ((e >= 100 && e <= 145) || u == 0) ? 1 : 0;
    unsigned long long b = __ballot(sane);
    return (__popcll(b) >= 48) ? 1 : 0; // 1 = bf16, 0 = fp32
}

// ---------------------------------------------------------------------------
// One dispatch converts x + 4 weights; 8192 elems/block.
// ---------------------------------------------------------------------------
__global__ __launch_bounds__(256) void convert_all_kernel(
    const void* __restrict__ x,  const void* __restrict__ wq,
    const void* __restrict__ wk, const void* __restrict__ wv,
    const void* __restrict__ wo,
    short* __restrict__ xb, short* __restrict__ wqb, short* __restrict__ wkb,
    short* __restrict__ wvb, short* __restrict__ wob)
{
    const int f = detect_bf16((const unsigned short*)x);
    int bid = blockIdx.x;
    const void* src; short* dst; int base;
    if (bid < 512) { src = x; dst = xb; base = bid; }
    else {
        int w = (bid - 512) >> 7, lb = (bid - 512) & 127;
        src = (w == 0) ? wq : (w == 1) ? wk : (w == 2) ? wv : wo;
        dst = (w == 0) ? wqb : (w == 1) ? wkb : (w == 2) ? wvb : wob;
        base = lb;
    }
    int i0 = base * 8192 + (int)threadIdx.x * 8;
    #pragma unroll
    for (int r = 0; r < 4; ++r) {
        int i = i0 + r * 2048;
        if (f) {
            *(short8*)(dst + i) = *(const short8*)((const short*)src + i);
        } else {
            const float* s = (const float*)src + i;
            short8 o;
            #pragma unroll
            for (int j = 0; j < 8; ++j) o[j] = f2bf(s[j]);
            *(short8*)(dst + i) = o;
        }
    }
}

// ---------------------------------------------------------------------------
// GEMM core, global_load_lds staging (m97 structure). C[m,n]=sum_k A[m,k]B[n,k].
// Tile: MROWS x 128, BK=64, K=1024. 4 waves (2x2). XOR chunk swizzle folded
// into the per-lane GLOBAL source address; LDS writes stay linear (lane*16B).
// ---------------------------------------------------------------------------
template<int MROWS>
__device__ __forceinline__ void gemm_core_lds(
    const short* __restrict__ A, const short* __restrict__ B,
    short* SM, int mbase, int nbase, f32x4 (*acc)[4])
{
    constexpr int TA = MROWS / 32;
    short* As = SM;
    short* Bs = SM + MROWS * 64;

    const int tid = threadIdx.x;
    const int wave = tid >> 6, lane = tid & 63;
    const int wm = wave >> 1, wn = wave & 1;
    const int lr = lane & 15;
    const int srow = lane >> 3, jcl = lane & 7;
    const int jc = (jcl ^ srow) * 8;   // (r&7)==srow for all staged rows

    #pragma unroll
    for (int a = 0; a < TA; ++a)
        #pragma unroll
        for (int b = 0; b < 4; ++b) acc[a][b] = (f32x4){0, 0, 0, 0};

    const short* aA[TA]; short* lA[TA];
    const short* aB[4];  short* lB[4];
    #pragma unroll
    for (int t = 0; t < TA; ++t) {
        int w = wave * TA + t;
        aA[t] = A + (size_t)(mbase + w * 8 + srow) * TD + jc;
        lA[t] = As + w * 512;
    }
    #pragma unroll
    for (int t = 0; t < 4; ++t) {
        int w = wave * 4 + t;
        aB[t] = B + (size_t)(nbase + w * 8 + srow) * TD + jc;
        lB[t] = Bs + w * 512;
    }

    // prologue: issue k0=0 tile
    #pragma unroll
    for (int t = 0; t < TA; ++t) gload_lds16(aA[t], lA[t]);
    #pragma unroll
    for (int t = 0; t < 4; ++t)  gload_lds16(aB[t], lB[t]);

    for (int k0 = 0; k0 < TD; k0 += 64) {
        __syncthreads();   // staged loads complete (vmcnt drained per-wave)
        #pragma unroll
        for (int kk = 0; kk < 64; kk += 32) {
            const int cc = (kk >> 3) + (lane >> 4);
            const int csw = (cc ^ (lr & 7)) << 3;
            short8 af[TA], bf[4];
            #pragma unroll
            for (int a = 0; a < TA; ++a)
                af[a] = *(const short8*)&As[(wm * (MROWS / 2) + a * 16 + lr) * 64 + csw];
            #pragma unroll
            for (int b = 0; b < 4; ++b)
                bf[b] = *(const short8*)&Bs[(wn * 64 + b * 16 + lr) * 64 + csw];
            #pragma unroll
            for (int a = 0; a < TA; ++a)
                #pragma unroll
                for (int b = 0; b < 4; ++b)
                    acc[a][b] = __builtin_amdgcn_mfma_f32_16x16x32_bf16(af[a], bf[b], acc[a][b], 0, 0, 0);
        }
        if (k0 + 64 < TD) {
            __syncthreads();   // all LDS reads done; safe to overwrite
            #pragma unroll
            for (int t = 0; t < TA; ++t) gload_lds16(aA[t] + k0 + 64, lA[t]);
            #pragma unroll
            for (int t = 0; t < 4; ++t)  gload_lds16(aB[t] + k0 + 64, lB[t]);
        }
    }
}

// ---------------------------------------------------------------------------
// QKV projection; 128x128 tiles, grid (32, 8, 3).
// Q,K out [B,H,T,64] via LDS-transpose epilogue; V out [B,H,64,T].
// Q is PRE-SCALED by SCALE_LOG2 so attention computes P = exp2(S) directly.
// ---------------------------------------------------------------------------
__global__ __launch_bounds__(256, 3) void qkv_gemm_kernel(
    const short* __restrict__ x,
    const short* __restrict__ Wq, const short* __restrict__ Wk,
    const short* __restrict__ Wv,
    short* __restrict__ Qo, short* __restrict__ Ko, short* __restrict__ Vo)
{
    const short* W = (blockIdx.z == 0) ? Wq : (blockIdx.z == 1) ? Wk : Wv;
    short* Out = (blockIdx.z == 0) ? Qo : (blockIdx.z == 1) ? Ko : Vo;
    const bool transposeV = (blockIdx.z == 2);
    const float qscale = (blockIdx.z == 0) ? SCALE_LOG2 : 1.0f;

    __shared__ __align__(16) short SM[128 * 64 * 2];

    const int mbase = blockIdx.x * 128, nbase = blockIdx.y * 128;
    f32x4 acc[4][4];
    gemm_core_lds<128>(x, W, SM, mbase, nbase, acc);

    const int tid = threadIdx.x;
    const int wave = tid >> 6, lane = tid & 63;
    const int wm = wave >> 1, wn = wave & 1;
    const int lr = lane & 15;
    const int g4 = (lane >> 4) * 4;

    if (transposeV) {
        #pragma unroll
        for (int a = 0; a < 4; ++a) {
            #pragma unroll
            for (int b = 0; b < 4; ++b) {
                int m0 = mbase + wm * 64 + a * 16 + g4;
                int n = nbase + wn * 64 + b * 16 + lr;
                int bb = m0 >> 11, t0 = m0 & (TT - 1);
                int h = n >> 6, hd = n & 63;
                ushort4v pk;
                #pragma unroll
                for (int i = 0; i < 4; ++i) pk[i] = (unsigned short)f2bf(acc[a][b][i]);
                *(ushort4v*)&Out[((size_t)(bb * TH + h) * 64 + hd) * TT + t0] = pk;
            }
        }
    } else {
        short* Cs = SM;
        #pragma unroll
        for (int p = 0; p < 2; ++p) {
            __syncthreads();
            if (wn == p) {
                #pragma unroll
                for (int a = 0; a < 4; ++a)
                    #pragma unroll
                    for (int b = 0; b < 4; ++b)
                        #pragma unroll
                        for (int i = 0; i < 4; ++i) {
                            int ml = wm * 64 + a * 16 + g4 + i;
                            int nl = b * 16 + lr;
                            Cs[ml * 72 + nl] = f2bf(acc[a][b][i] * qscale);
                        }
            }
            __syncthreads();
            int tl = tid >> 1, hc = (tid & 1) * 32;
            int h = (nbase >> 6) + p;
            int m = mbase + tl;
            int bb = m >> 11, t = m & (TT - 1);
            size_t base = (((size_t)(bb * TH + h) * TT + t) << 6) + hc;
            #pragma unroll
            for (int q = 0; q < 4; ++q)
                *(short8*)&Out[base + q * 8] = *(short8*)&Cs[tl * 72 + hc + q * 8];
        }
    }
}

// ---------------------------------------------------------------------------
// Output projection; 64x128 tiles, grid (64, 8).
// ---------------------------------------------------------------------------
__global__ __launch_bounds__(256, 3) void out_gemm_kernel(
    const short* __restrict__ A, const short* __restrict__ W,
    void* __restrict__ C, const unsigned short* __restrict__ xq)
{
    const int f = detect_bf16(xq);

    __shared__ __align__(16) short SM[64 * 64 + 128 * 64];

    const int mbase = blockIdx.x * 64, nbase = blockIdx.y * 128;
    f32x4 acc[2][4];
    gemm_core_lds<64>(A, W, SM, mbase, nbase, acc);

    const int tid = threadIdx.x;
    const int wave = tid >> 6, lane = tid & 63;
    const int wm = wave >> 1, wn = wave & 1;
    const int lr = lane & 15;
    const int g4 = (lane >> 4) * 4;

    #pragma unroll
    for (int a = 0; a < 2; ++a) {
        #pragma unroll
        for (int b = 0; b < 4; ++b) {
            #pragma unroll
            for (int i = 0; i < 4; ++i) {
                int m = mbase + wm * 32 + a * 16 + g4 + i;
                int n = nbase + wn * 64 + b * 16 + lr;
                if (f) ((short*)C)[(size_t)m * TD + n] = f2bf(acc[a][b][i]);
                else   ((float*)C)[(size_t)m * TD + n] = acc[a][b][i];
            }
        }
    }
}

// ---------------------------------------------------------------------------
// SINGLE-PASS flash attention. 32x32 MFMA, swapped QK^T (S^T = K Q^T),
// softmax in registers: P = exp2(S) (scale pre-folded into Q). 128 q-rows/
// block (4 waves x 32 q-rows). K/V staged via global_load_lds into a
// 3-BUFFER LDS RING with COUNTED vmcnt (T4) + raw s_barrier:
//   it: wait vmcnt(4 | 0-on-last) -> sched_barrier(0) -> s_barrier
//       -> issue stage(it+2) -> compute buf[it%3]
// Waves are symmetric, so per-wave vmcnt(4)+barrier makes tile `it`
// collectively complete; stage(it+2) after the barrier can't overwrite
// buf[(it-1)%3] while any wave still reads it. DMA never drained in-loop.
// grid (32 bh, 16 y); qt = (y<8)?15-y:y-8. Epilogue: 1/l normalize, LDS
// transpose, direct [B,T,H,64] store.
// ---------------------------------------------------------------------------
__global__ __launch_bounds__(256, 3) void attn_fused_kernel(
    const short* __restrict__ Q, const short* __restrict__ K,
    const short* __restrict__ V, short* __restrict__ AO)
{
    const int bh = blockIdx.x;
    const int y = blockIdx.y;
    const int qt = (y < 8) ? (15 - y) : (y - 8);   // heavy first; pairs sum 15
    const int te = 2 * qt + 2;                     // k-tiles [0, te), te >= 2

    const int qbase = qt * 128;
    const int b = bh >> 4, h = bh & 15;
    const short* Qp = Q + (size_t)bh * TT * 64;
    const short* Kp = K + (size_t)bh * TT * 64;
    const short* Vp = V + (size_t)bh * 64 * TT;   // V^T: [64][TT]

    __shared__ __align__(16) short SMEM[24576];   // Ks ring[3][64][64] | Vt ring[3][64][64]
    short* KsL = SMEM;            // buf stride 4096 shorts
    short* VtL = SMEM + 12288;

    const int tid = threadIdx.x;
    const int wave = tid >> 6, lane = tid & 63;
    const int l31 = lane & 31, g = lane >> 5;
    const int lsw = (l31 & 7);    // XOR swizzle key for ds_reads

    // staging via gload_lds: round r covers rows r*32 + wave*8 + (lane>>3),
    // chunk lane&7; global source pre-swizzled: chunk ^= row&7; LDS linear.
    const int srow_off = wave * 8 + (lane >> 3);   // 0..31
    const int schunk = lane & 7;

    // Q fragments (B-operand): lane holds q-row qrow, 64 hd in 4 chunks
    const int qrow0 = qbase + wave * 32;      // wave's min q (uniform)
    const int qrow = qrow0 + l31;             // this lane's q row
    short8 qf[4];
    #pragma unroll
    for (int c = 0; c < 4; ++c)
        qf[c] = *(const short8*)&Qp[(size_t)qrow * 64 + c * 16 + g * 8];

    short8 ones8;
    #pragma unroll
    for (int i = 0; i < 8; ++i) ones8[i] = BF16_ONE;

    f32x16 Oa[2];                // O^T accum: [hd-tile][ (hd-row, q) frag ]
    Oa[0] = zero16(); Oa[1] = zero16();
    f32x16 La = zero16();        // l (all rows identical = l[q=l31])

    // stage tile `it` into ring slot it%3 (4 gload_lds per thread)
    auto stage = [&](int it, int slot) {
        const int kn = it * 64;
        const int db = slot * 4096;
        #pragma unroll
        for (int r = 0; r < 2; ++r) {
            int row = r * 32 + srow_off;
            gload_lds16(&Kp[(size_t)(kn + row) * 64 + ((schunk ^ (row & 7)) * 8)],
                        KsL + db + (r * 32 + wave * 8) * 64);
            gload_lds16(&Vp[(size_t)row * TT + kn + ((schunk ^ (row & 7)) * 8)],
                        VtL + db + (r * 32 + wave * 8) * 64);
        }
    };

    // prologue: stage tiles 0 and 1 (te >= 2 always) -> 8 outstanding/wave
    stage(0, 0);
    stage(1, 1);

    int cur = 0;                 // it % 3
    for (int it = 0; it < te; ++it) {
        const bool more1 = (it + 1) < te;

        // counted wait: newest 4 outstanding are stage(it+1)'s; tile `it`
        // (and everything older, incl. Q loads) is complete at vmcnt(4).
        if (more1) asm volatile("s_waitcnt vmcnt(4)" ::: "memory");
        else       asm volatile("s_waitcnt vmcnt(0)" ::: "memory");
        __builtin_amdgcn_sched_barrier(0);
        __builtin_amdgcn_s_barrier();   // all waves: tile `it` ready; all
                                        // waves done reading buf[(it-1)%3]

        if (it + 2 < te) {
            int slot2 = cur + 2; if (slot2 >= 3) slot2 -= 3;
            stage(it + 2, slot2);       // overwrites buf[(it-1)%3] -- safe
        }

        const int kt = it * 64;
        const int bb = cur * 4096;
        const bool act0 = (kt) <= qrow0 + 31;        // subtile k [kt, kt+32)
        const bool act1 = (kt + 32) <= qrow0 + 31;   // subtile k [kt+32, kt+64)

        // ---- phase 1: QK^T for both subtiles (MFMA cluster) ----
        f32x16 S[2];
        __builtin_amdgcn_s_setprio(1);
        if (act0) {
            S[0] = zero16();
            #pragma unroll
            for (int c = 0; c < 4; ++c) {
                short8 kf = *(const short8*)&KsL[bb + (l31) * 64 + (((2 * c + g) ^ lsw) * 8)];
                S[0] = __builtin_amdgcn_mfma_f32_32x32x16_bf16(kf, qf[c], S[0], 0, 0, 0);
            }
        }
        if (act1) {
            S[1] = zero16();
            #pragma unroll
            for (int c = 0; c < 4; ++c) {
                short8 kf = *(const short8*)&KsL[bb + (32 + l31) * 64 + (((2 * c + g) ^ lsw) * 8)];
                S[1] = __builtin_amdgcn_mfma_f32_32x32x16_bf16(kf, qf[c], S[1], 0, 0, 0);
            }
        }
        __builtin_amdgcn_s_setprio(0);

        // ---- phase 2: P = exp2(S) + bf16 pack for both subtiles (VALU) ----
        short8 pf[2][2];
        #pragma unroll
        for (int t = 0; t < 2; ++t) {
            const bool act = t ? act1 : act0;
            if (!act) continue;
            const int kb32 = kt + t * 32;
            const bool partm = (kb32 + 31) > qrow0;
            if (partm) {
                #pragma unroll
                for (int r = 0; r < 16; ++r) {
                    int kglob = kb32 + (r & 3) + ((r >> 2) << 3) + 4 * g;
                    S[t][r] = fast_exp2(kglob > qrow ? NEG_BIG : S[t][r]);
                }
            } else {
                #pragma unroll
                for (int r = 0; r < 16; ++r)
                    S[t][r] = fast_exp2(S[t][r]);
            }
            // pack to bf16 B-fragments in-register (T12)
            unsigned int w[8];
            #pragma unroll
            for (int j = 0; j < 2; ++j) {
                unsigned int a, bq;
                asm("v_cvt_pk_bf16_f32 %0, %1, %2" : "=v"(a) : "v"(S[t][2 * j]), "v"(S[t][2 * j + 1]));
                asm("v_cvt_pk_bf16_f32 %0, %1, %2" : "=v"(bq) : "v"(S[t][2 * j + 4]), "v"(S[t][2 * j + 5]));
                asm("v_permlane32_swap_b32 %0, %1" : "+v"(a), "+v"(bq));
                w[j] = a; w[j + 2] = bq;
                unsigned int a2, b2;
                asm("v_cvt_pk_bf16_f32 %0, %1, %2" : "=v"(a2) : "v"(S[t][8 + 2 * j]), "v"(S[t][9 + 2 * j]));
                asm("v_cvt_pk_bf16_f32 %0, %1, %2" : "=v"(b2) : "v"(S[t][12 + 2 * j]), "v"(S[t][13 + 2 * j]));
                asm("v_permlane32_swap_b32 %0, %1" : "+v"(a2), "+v"(b2));
                w[4 + j] = a2; w[6 + j] = b2;
            }
            u32x4 u0 = {w[0], w[1], w[2], w[3]};
            u32x4 u1 = {w[4], w[5], w[6], w[7]};
            pf[t][0] = __builtin_bit_cast(short8, u0);  // k [kb32, kb32+16)
            pf[t][1] = __builtin_bit_cast(short8, u1);  // k [kb32+16, +32)
        }

        // ---- phase 3: PV + l for both subtiles (MFMA cluster) ----
        __builtin_amdgcn_s_setprio(1);
        #pragma unroll
        for (int t = 0; t < 2; ++t) {
            const bool act = t ? act1 : act0;
            if (!act) continue;
            #pragma unroll
            for (int hh = 0; hh < 2; ++hh) {
                short8 vf0 = *(const short8*)&VtL[bb + (hh * 32 + l31) * 64 + (((4 * t + g) ^ lsw) * 8)];
                Oa[hh] = __builtin_amdgcn_mfma_f32_32x32x16_bf16(vf0, pf[t][0], Oa[hh], 0, 0, 0);
                short8 vf1 = *(const short8*)&VtL[bb + (hh * 32 + l31) * 64 + (((4 * t + 2 + g) ^ lsw) * 8)];
                Oa[hh] = __builtin_amdgcn_mfma_f32_32x32x16_bf16(vf1, pf[t][1], Oa[hh], 0, 0, 0);
            }
            La = __builtin_amdgcn_mfma_f32_32x32x16_bf16(ones8, pf[t][0], La, 0, 0, 0);
            La = __builtin_amdgcn_mfma_f32_32x32x16_bf16(ones8, pf[t][1], La, 0, 0, 0);
        }
        __builtin_amdgcn_s_setprio(0);

        ++cur; if (cur == 3) cur = 0;
        // NO trailing barrier, NO vmcnt(0): next iteration's counted wait +
        // barrier provide the ordering.
    }

    __syncthreads();   // all waves past their last compute; SMEM reusable

    // epilogue: normalize by 1/l, O^T -> LDS f32 -> transposed coalesced
    // bf16 store direct to AO [B,T,H*64].
    const float rl = 1.0f / La[0];
    float* OT = (float*)SMEM;    // [64][132] f32 = 33792 B <= 49152 B
    #pragma unroll
    for (int hh = 0; hh < 2; ++hh)
        #pragma unroll
        for (int r = 0; r < 16; ++r) {
            int hd = hh * 32 + (r & 3) + ((r >> 2) << 3) + 4 * g;
            OT[hd * 132 + wave * 32 + l31] = Oa[hh][r] * rl;
        }
    __syncthreads();
    {
        const int q = tid >> 1, hc = (tid & 1) * 32;
        short tmp[32];
        #pragma unroll
        for (int i = 0; i < 32; ++i)
            tmp[i] = f2bf(OT[(hc + i) * 132 + q]);
        size_t ab = ((size_t)(b * TT + qbase + q) << 10) + h * 64 + hc;
        #pragma unroll
        for (int v = 0; v < 4; ++v)
            *(short8*)&AO[ab + v * 8] = *(short8*)&tmp[v * 8];
    }
}

// ---------------------------------------------------------------------------
extern "C" void kernel_launch(void* const* d_in, const int* in_sizes, int n_in,
                              void* d_out, int out_size, void* d_ws, size_t ws_size,
                              hipStream_t stream)
{
    char* ws = (char*)d_ws;
    const size_t XB  = (size_t)TM * TD * 2;   // 8 MiB bf16 x
    const size_t WB  = (size_t)TD * TD * 2;   // 2 MiB bf16 weight
    const size_t BUF = (size_t)TM * TD * 2;   // 8 MiB activation

    short* xb  = (short*)(ws + 256);
    short* Wqb = (short*)(ws + 256 + XB);
    short* Wkb = (short*)(ws + 256 + XB + WB);
    short* Wvb = (short*)(ws + 256 + XB + 2 * WB);
    short* Wob = (short*)(ws + 256 + XB + 3 * WB);
    char*  act = ws + 256 + XB + 4 * WB;
    short* Qb = (short*)(act);
    short* Kb = (short*)(act + BUF);
    short* Vb = (short*)(act + 2 * BUF);   // V^T [B,H,64,T]
    short* Ab = (short*)(act + 3 * BUF);

    dim3 blk(256);
    convert_all_kernel<<<dim3(512 + 4 * 128), blk, 0, stream>>>(
        d_in[0], d_in[1], d_in[2], d_in[3], d_in[4], xb, Wqb, Wkb, Wvb, Wob);
    qkv_gemm_kernel<<<dim3(TM / 128, TD / 128, 3), blk, 0, stream>>>(xb, Wqb, Wkb, Wvb, Qb, Kb, Vb);
    attn_fused_kernel<<<dim3(32, 16), blk, 0, stream>>>(Qb, Kb, Vb, Ab);
    out_gemm_kernel<<<dim3(TM / 64, TD / 128), blk, 0, stream>>>(
        Ab, Wob, d_out, (const unsigned short*)d_in[0]);
}

// Round 13
// 173.480 us; speedup vs baseline: 1.0478x; 1.0478x over previous
//
#include <hip/hip_runtime.h>
#include <hip/hip_bf16.h>

// Problem: B=2, T=2048, D=1024, H=16, HD=64.
// Runtime-detect fp32 vs bf16 inputs (inline, per-wave); canonicalize to bf16.
// convert_all -> qkv gemm (128x128, global_load_lds staging m97-style;
// Q,K:[B,H,T,64] via LDS-transpose epilogue; V:[B,H,64,T]; Q PRE-SCALED by
// log2(e)/sqrt(64)) -> SINGLE-PASS flash attention (grid (32 bh, 16 qt),
// qt = (y<8)?15-y:y-8; 32x32 MFMA, swapped QK^T, K/V gload_lds dbuf w/ XOR
// chunk swizzle, 1 barrier/tile, P = exp2(S), in-register pack via
// cvt_pk_bf16 + permlane32_swap, MFMA ones-row l, setprio, in-epilogue 1/l
// normalize + direct [B,T,H,64] store) -> out gemm (64x128).
// [R13: resubmission of the R7-proven baseline; R12 failed on GPU
//  acquisition (infrastructure), never measured.]

#define TB 2
#define TT 2048
#define TD 1024
#define TH 16
#define TM (TB * TT) // 4096

#define NEG_BIG (-1e30f)
#define SCALE_LOG2 0.18033688f  // (1/sqrt(64)) * log2(e), folded into Q
#define BF16_ONE ((short)0x3F80)

typedef __attribute__((ext_vector_type(8))) short short8;
typedef __attribute__((ext_vector_type(4))) float f32x4;
typedef __attribute__((ext_vector_type(16))) float f32x16;
typedef __attribute__((ext_vector_type(4))) unsigned short ushort4v;
typedef __attribute__((ext_vector_type(4))) unsigned int u32x4;

__device__ __forceinline__ short f2bf(float f) {
    __hip_bfloat16 h = __float2bfloat16(f);
    return __builtin_bit_cast(short, h);
}

__device__ __forceinline__ float bf2f(short u) {
    unsigned int x = ((unsigned int)(unsigned short)u) << 16;
    return __builtin_bit_cast(float, x);
}

__device__ __forceinline__ float fast_exp2(float x) {
#if __has_builtin(__builtin_amdgcn_exp2f)
    return __builtin_amdgcn_exp2f(x);
#else
    return exp2f(x);
#endif
}

__device__ __forceinline__ f32x16 zero16() {
    f32x16 v;
    #pragma unroll
    for (int i = 0; i < 16; ++i) v[i] = 0.f;
    return v;
}

// Async global->LDS DMA, 16 B/lane. LDS dest is wave-uniform base + lane*16;
// global src is per-lane (pre-swizzled). Completion counted by vmcnt; the
// compiler's s_waitcnt vmcnt(0) before s_barrier (__syncthreads) drains it.
__device__ __forceinline__ void gload_lds16(const short* g, short* l) {
    __builtin_amdgcn_global_load_lds(
        (const __attribute__((address_space(1))) unsigned int*)g,
        (__attribute__((address_space(3))) unsigned int*)l,
        16, 0, 0);
}

// Inline dtype detect: sample even u16s of x; uniform per wave.
__device__ __forceinline__ int detect_bf16(const unsigned short* xq) {
    int lane = threadIdx.x & 63;
    unsigned short u = xq[lane * 2];
    int e = (u >> 7) & 0xFF;
    int sane = ((e >= 100 && e <= 145) || u == 0) ? 1 : 0;
    unsigned long long b = __ballot(sane);
    return (__popcll(b) >= 48) ? 1 : 0; // 1 = bf16, 0 = fp32
}

// ---------------------------------------------------------------------------
// One dispatch converts x + 4 weights; 8192 elems/block.
// ---------------------------------------------------------------------------
__global__ __launch_bounds__(256) void convert_all_kernel(
    const void* __restrict__ x,  const void* __restrict__ wq,
    const void* __restrict__ wk, const void* __restrict__ wv,
    const void* __restrict__ wo,
    short* __restrict__ xb, short* __restrict__ wqb, short* __restrict__ wkb,
    short* __restrict__ wvb, short* __restrict__ wob)
{
    const int f = detect_bf16((const unsigned short*)x);
    int bid = blockIdx.x;
    const void* src; short* dst; int base;
    if (bid < 512) { src = x; dst = xb; base = bid; }
    else {
        int w = (bid - 512) >> 7, lb = (bid - 512) & 127;
        src = (w == 0) ? wq : (w == 1) ? wk : (w == 2) ? wv : wo;
        dst = (w == 0) ? wqb : (w == 1) ? wkb : (w == 2) ? wvb : wob;
        base = lb;
    }
    int i0 = base * 8192 + (int)threadIdx.x * 8;
    #pragma unroll
    for (int r = 0; r < 4; ++r) {
        int i = i0 + r * 2048;
        if (f) {
            *(short8*)(dst + i) = *(const short8*)((const short*)src + i);
        } else {
            const float* s = (const float*)src + i;
            short8 o;
            #pragma unroll
            for (int j = 0; j < 8; ++j) o[j] = f2bf(s[j]);
            *(short8*)(dst + i) = o;
        }
    }
}

// ---------------------------------------------------------------------------
// GEMM core, global_load_lds staging (m97 structure). C[m,n]=sum_k A[m,k]B[n,k].
// Tile: MROWS x 128, BK=64, K=1024. 4 waves (2x2). XOR chunk swizzle folded
// into the per-lane GLOBAL source address; LDS writes stay linear (lane*16B).
// ---------------------------------------------------------------------------
template<int MROWS>
__device__ __forceinline__ void gemm_core_lds(
    const short* __restrict__ A, const short* __restrict__ B,
    short* SM, int mbase, int nbase, f32x4 (*acc)[4])
{
    constexpr int TA = MROWS / 32;
    short* As = SM;
    short* Bs = SM + MROWS * 64;

    const int tid = threadIdx.x;
    const int wave = tid >> 6, lane = tid & 63;
    const int wm = wave >> 1, wn = wave & 1;
    const int lr = lane & 15;
    const int srow = lane >> 3, jcl = lane & 7;
    const int jc = (jcl ^ srow) * 8;   // (r&7)==srow for all staged rows

    #pragma unroll
    for (int a = 0; a < TA; ++a)
        #pragma unroll
        for (int b = 0; b < 4; ++b) acc[a][b] = (f32x4){0, 0, 0, 0};

    const short* aA[TA]; short* lA[TA];
    const short* aB[4];  short* lB[4];
    #pragma unroll
    for (int t = 0; t < TA; ++t) {
        int w = wave * TA + t;
        aA[t] = A + (size_t)(mbase + w * 8 + srow) * TD + jc;
        lA[t] = As + w * 512;
    }
    #pragma unroll
    for (int t = 0; t < 4; ++t) {
        int w = wave * 4 + t;
        aB[t] = B + (size_t)(nbase + w * 8 + srow) * TD + jc;
        lB[t] = Bs + w * 512;
    }

    // prologue: issue k0=0 tile
    #pragma unroll
    for (int t = 0; t < TA; ++t) gload_lds16(aA[t], lA[t]);
    #pragma unroll
    for (int t = 0; t < 4; ++t)  gload_lds16(aB[t], lB[t]);

    for (int k0 = 0; k0 < TD; k0 += 64) {
        __syncthreads();   // staged loads complete (vmcnt drained per-wave)
        #pragma unroll
        for (int kk = 0; kk < 64; kk += 32) {
            const int cc = (kk >> 3) + (lane >> 4);
            const int csw = (cc ^ (lr & 7)) << 3;
            short8 af[TA], bf[4];
            #pragma unroll
            for (int a = 0; a < TA; ++a)
                af[a] = *(const short8*)&As[(wm * (MROWS / 2) + a * 16 + lr) * 64 + csw];
            #pragma unroll
            for (int b = 0; b < 4; ++b)
                bf[b] = *(const short8*)&Bs[(wn * 64 + b * 16 + lr) * 64 + csw];
            #pragma unroll
            for (int a = 0; a < TA; ++a)
                #pragma unroll
                for (int b = 0; b < 4; ++b)
                    acc[a][b] = __builtin_amdgcn_mfma_f32_16x16x32_bf16(af[a], bf[b], acc[a][b], 0, 0, 0);
        }
        if (k0 + 64 < TD) {
            __syncthreads();   // all LDS reads done; safe to overwrite
            #pragma unroll
            for (int t = 0; t < TA; ++t) gload_lds16(aA[t] + k0 + 64, lA[t]);
            #pragma unroll
            for (int t = 0; t < 4; ++t)  gload_lds16(aB[t] + k0 + 64, lB[t]);
        }
    }
}

// ---------------------------------------------------------------------------
// QKV projection; 128x128 tiles, grid (32, 8, 3).
// Q,K out [B,H,T,64] via LDS-transpose epilogue; V out [B,H,64,T].
// Q is PRE-SCALED by SCALE_LOG2 so attention computes P = exp2(S) directly.
// ---------------------------------------------------------------------------
__global__ __launch_bounds__(256, 3) void qkv_gemm_kernel(
    const short* __restrict__ x,
    const short* __restrict__ Wq, const short* __restrict__ Wk,
    const short* __restrict__ Wv,
    short* __restrict__ Qo, short* __restrict__ Ko, short* __restrict__ Vo)
{
    const short* W = (blockIdx.z == 0) ? Wq : (blockIdx.z == 1) ? Wk : Wv;
    short* Out = (blockIdx.z == 0) ? Qo : (blockIdx.z == 1) ? Ko : Vo;
    const bool transposeV = (blockIdx.z == 2);
    const float qscale = (blockIdx.z == 0) ? SCALE_LOG2 : 1.0f;

    __shared__ __align__(16) short SM[128 * 64 * 2];

    const int mbase = blockIdx.x * 128, nbase = blockIdx.y * 128;
    f32x4 acc[4][4];
    gemm_core_lds<128>(x, W, SM, mbase, nbase, acc);

    const int tid = threadIdx.x;
    const int wave = tid >> 6, lane = tid & 63;
    const int wm = wave >> 1, wn = wave & 1;
    const int lr = lane & 15;
    const int g4 = (lane >> 4) * 4;

    if (transposeV) {
        #pragma unroll
        for (int a = 0; a < 4; ++a) {
            #pragma unroll
            for (int b = 0; b < 4; ++b) {
                int m0 = mbase + wm * 64 + a * 16 + g4;
                int n = nbase + wn * 64 + b * 16 + lr;
                int bb = m0 >> 11, t0 = m0 & (TT - 1);
                int h = n >> 6, hd = n & 63;
                ushort4v pk;
                #pragma unroll
                for (int i = 0; i < 4; ++i) pk[i] = (unsigned short)f2bf(acc[a][b][i]);
                *(ushort4v*)&Out[((size_t)(bb * TH + h) * 64 + hd) * TT + t0] = pk;
            }
        }
    } else {
        short* Cs = SM;
        #pragma unroll
        for (int p = 0; p < 2; ++p) {
            __syncthreads();
            if (wn == p) {
                #pragma unroll
                for (int a = 0; a < 4; ++a)
                    #pragma unroll
                    for (int b = 0; b < 4; ++b)
                        #pragma unroll
                        for (int i = 0; i < 4; ++i) {
                            int ml = wm * 64 + a * 16 + g4 + i;
                            int nl = b * 16 + lr;
                            Cs[ml * 72 + nl] = f2bf(acc[a][b][i] * qscale);
                        }
            }
            __syncthreads();
            int tl = tid >> 1, hc = (tid & 1) * 32;
            int h = (nbase >> 6) + p;
            int m = mbase + tl;
            int bb = m >> 11, t = m & (TT - 1);
            size_t base = (((size_t)(bb * TH + h) * TT + t) << 6) + hc;
            #pragma unroll
            for (int q = 0; q < 4; ++q)
                *(short8*)&Out[base + q * 8] = *(short8*)&Cs[tl * 72 + hc + q * 8];
        }
    }
}

// ---------------------------------------------------------------------------
// Output projection; 64x128 tiles, grid (64, 8).
// ---------------------------------------------------------------------------
__global__ __launch_bounds__(256, 3) void out_gemm_kernel(
    const short* __restrict__ A, const short* __restrict__ W,
    void* __restrict__ C, const unsigned short* __restrict__ xq)
{
    const int f = detect_bf16(xq);

    __shared__ __align__(16) short SM[64 * 64 + 128 * 64];

    const int mbase = blockIdx.x * 64, nbase = blockIdx.y * 128;
    f32x4 acc[2][4];
    gemm_core_lds<64>(A, W, SM, mbase, nbase, acc);

    const int tid = threadIdx.x;
    const int wave = tid >> 6, lane = tid & 63;
    const int wm = wave >> 1, wn = wave & 1;
    const int lr = lane & 15;
    const int g4 = (lane >> 4) * 4;

    #pragma unroll
    for (int a = 0; a < 2; ++a) {
        #pragma unroll
        for (int b = 0; b < 4; ++b) {
            #pragma unroll
            for (int i = 0; i < 4; ++i) {
                int m = mbase + wm * 32 + a * 16 + g4 + i;
                int n = nbase + wn * 64 + b * 16 + lr;
                if (f) ((short*)C)[(size_t)m * TD + n] = f2bf(acc[a][b][i]);
                else   ((float*)C)[(size_t)m * TD + n] = acc[a][b][i];
            }
        }
    }
}

// ---------------------------------------------------------------------------
// SINGLE-PASS flash attention (no split/merge). 32x32 MFMA, swapped QK^T
// (S^T = K Q^T), softmax fully in registers: P = exp2(S) (scale pre-folded
// into Q). P->bf16 via v_cvt_pk_bf16_f32 + v_permlane32_swap_b32; l on the
// MFMA pipe via ones-A-frag. 128 q-rows/block (4 waves x 32 q-rows). K/V
// staged via global_load_lds into [2][64][64] linear LDS with XOR chunk
// swizzle on BOTH sides (rule #21); dbuf, staging issued at loop TOP; ONE
// barrier per 64-k tile. grid (32 bh, 16 y); qt = (y<8)?15-y:y-8 so RR
// co-resident blocks y,y+8 carry 36 k-tiles/CU total (balanced, no merge).
// Epilogue: normalize by 1/l in-register, LDS transpose, direct [B,T,H,64].
// ---------------------------------------------------------------------------
__global__ __launch_bounds__(256, 3) void attn_fused_kernel(
    const short* __restrict__ Q, const short* __restrict__ K,
    const short* __restrict__ V, short* __restrict__ AO)
{
    const int bh = blockIdx.x;
    const int y = blockIdx.y;
    const int qt = (y < 8) ? (15 - y) : (y - 8);   // heavy first; pairs sum 15
    const int te = 2 * qt + 2;                     // k-tiles [0, te)

    const int qbase = qt * 128;
    const int b = bh >> 4, h = bh & 15;
    const short* Qp = Q + (size_t)bh * TT * 64;
    const short* Kp = K + (size_t)bh * TT * 64;
    const short* Vp = V + (size_t)bh * 64 * TT;   // V^T: [64][TT]

    __shared__ __align__(16) short SMEM[18432];   // Ks[2][64][64] | Vt[2][64][64] | (epilogue OT)
    short* KsL = SMEM;           // buf stride 4096 shorts
    short* VtL = SMEM + 8192;

    const int tid = threadIdx.x;
    const int wave = tid >> 6, lane = tid & 63;
    const int l31 = lane & 31, g = lane >> 5;
    const int lsw = (l31 & 7);   // XOR swizzle key for ds_reads

    // staging via gload_lds: round r covers rows r*32 + wave*8 + (lane>>3),
    // chunk lane&7; global source pre-swizzled: chunk ^= row&7; LDS linear.
    const int srow_off = wave * 8 + (lane >> 3);   // 0..31
    const int schunk = lane & 7;

    // Q fragments (B-operand): lane holds q-row qrow, 64 hd in 4 chunks
    const int qrow0 = qbase + wave * 32;      // wave's min q (uniform)
    const int qrow = qrow0 + l31;             // this lane's q row
    short8 qf[4];
    #pragma unroll
    for (int c = 0; c < 4; ++c)
        qf[c] = *(const short8*)&Qp[(size_t)qrow * 64 + c * 16 + g * 8];

    short8 ones8;
    #pragma unroll
    for (int i = 0; i < 8; ++i) ones8[i] = BF16_ONE;

    f32x16 Oa[2];                // O^T accum: [hd-tile][ (hd-row, q) frag ]
    Oa[0] = zero16(); Oa[1] = zero16();
    f32x16 La = zero16();        // l (all rows identical = l[q=l31])

    // prologue: stage first tile into buf 0 (DMA, drained by first barrier)
    #pragma unroll
    for (int r = 0; r < 2; ++r) {
        int row = r * 32 + srow_off;
        gload_lds16(&Kp[(size_t)row * 64 + ((schunk ^ (row & 7)) * 8)],
                    KsL + (r * 32 + wave * 8) * 64);
        gload_lds16(&Vp[(size_t)row * TT + ((schunk ^ (row & 7)) * 8)],
                    VtL + (r * 32 + wave * 8) * 64);
    }
    __syncthreads();

    int buf = 0;
    for (int it = 0; it < te; ++it) {
        const int kt = it * 64;
        const bool more = (it + 1) < te;

        // issue next tile's DMA into the alternate buffer NOW: it flies under
        // this tile's compute; the end-of-tile barrier's vmcnt drain covers it.
        if (more) {
            const int kn = kt + 64;
            const int db = (buf ^ 1) * 4096;
            #pragma unroll
            for (int r = 0; r < 2; ++r) {
                int row = r * 32 + srow_off;
                gload_lds16(&Kp[(size_t)(kn + row) * 64 + ((schunk ^ (row & 7)) * 8)],
                            KsL + db + (r * 32 + wave * 8) * 64);
                gload_lds16(&Vp[(size_t)row * TT + kn + ((schunk ^ (row & 7)) * 8)],
                            VtL + db + (r * 32 + wave * 8) * 64);
            }
        }

        const int bb = buf * 4096;
        const bool act0 = (kt) <= qrow0 + 31;        // subtile k [kt, kt+32)
        const bool act1 = (kt + 32) <= qrow0 + 31;   // subtile k [kt+32, kt+64)

        // ---- phase 1: QK^T for both subtiles (MFMA cluster) ----
        f32x16 S[2];
        __builtin_amdgcn_s_setprio(1);
        if (act0) {
            S[0] = zero16();
            #pragma unroll
            for (int c = 0; c < 4; ++c) {
                short8 kf = *(const short8*)&KsL[bb + (l31) * 64 + (((2 * c + g) ^ lsw) * 8)];
                S[0] = __builtin_amdgcn_mfma_f32_32x32x16_bf16(kf, qf[c], S[0], 0, 0, 0);
            }
        }
        if (act1) {
            S[1] = zero16();
            #pragma unroll
            for (int c = 0; c < 4; ++c) {
                short8 kf = *(const short8*)&KsL[bb + (32 + l31) * 64 + (((2 * c + g) ^ lsw) * 8)];
                S[1] = __builtin_amdgcn_mfma_f32_32x32x16_bf16(kf, qf[c], S[1], 0, 0, 0);
            }
        }
        __builtin_amdgcn_s_setprio(0);

        // ---- phase 2: P = exp2(S) + bf16 pack for both subtiles (VALU) ----
        short8 pf[2][2];
        #pragma unroll
        for (int t = 0; t < 2; ++t) {
            const bool act = t ? act1 : act0;
            if (!act) continue;
            const int kb32 = kt + t * 32;
            const bool partm = (kb32 + 31) > qrow0;
            if (partm) {
                #pragma unroll
                for (int r = 0; r < 16; ++r) {
                    int kglob = kb32 + (r & 3) + ((r >> 2) << 3) + 4 * g;
                    S[t][r] = fast_exp2(kglob > qrow ? NEG_BIG : S[t][r]);
                }
            } else {
                #pragma unroll
                for (int r = 0; r < 16; ++r)
                    S[t][r] = fast_exp2(S[t][r]);
            }
            // pack to bf16 B-fragments in-register (T12)
            unsigned int w[8];
            #pragma unroll
            for (int j = 0; j < 2; ++j) {
                unsigned int a, bq;
                asm("v_cvt_pk_bf16_f32 %0, %1, %2" : "=v"(a) : "v"(S[t][2 * j]), "v"(S[t][2 * j + 1]));
                asm("v_cvt_pk_bf16_f32 %0, %1, %2" : "=v"(bq) : "v"(S[t][2 * j + 4]), "v"(S[t][2 * j + 5]));
                asm("v_permlane32_swap_b32 %0, %1" : "+v"(a), "+v"(bq));
                w[j] = a; w[j + 2] = bq;
                unsigned int a2, b2;
                asm("v_cvt_pk_bf16_f32 %0, %1, %2" : "=v"(a2) : "v"(S[t][8 + 2 * j]), "v"(S[t][9 + 2 * j]));
                asm("v_cvt_pk_bf16_f32 %0, %1, %2" : "=v"(b2) : "v"(S[t][12 + 2 * j]), "v"(S[t][13 + 2 * j]));
                asm("v_permlane32_swap_b32 %0, %1" : "+v"(a2), "+v"(b2));
                w[4 + j] = a2; w[6 + j] = b2;
            }
            u32x4 u0 = {w[0], w[1], w[2], w[3]};
            u32x4 u1 = {w[4], w[5], w[6], w[7]};
            pf[t][0] = __builtin_bit_cast(short8, u0);  // k [kb32, kb32+16)
            pf[t][1] = __builtin_bit_cast(short8, u1);  // k [kb32+16, +32)
        }

        // ---- phase 3: PV + l for both subtiles (MFMA cluster) ----
        __builtin_amdgcn_s_setprio(1);
        #pragma unroll
        for (int t = 0; t < 2; ++t) {
            const bool act = t ? act1 : act0;
            if (!act) continue;
            #pragma unroll
            for (int hh = 0; hh < 2; ++hh) {
                short8 vf0 = *(const short8*)&VtL[bb + (hh * 32 + l31) * 64 + (((4 * t + g) ^ lsw) * 8)];
                Oa[hh] = __builtin_amdgcn_mfma_f32_32x32x16_bf16(vf0, pf[t][0], Oa[hh], 0, 0, 0);
                short8 vf1 = *(const short8*)&VtL[bb + (hh * 32 + l31) * 64 + (((4 * t + 2 + g) ^ lsw) * 8)];
                Oa[hh] = __builtin_amdgcn_mfma_f32_32x32x16_bf16(vf1, pf[t][1], Oa[hh], 0, 0, 0);
            }
            La = __builtin_amdgcn_mfma_f32_32x32x16_bf16(ones8, pf[t][0], La, 0, 0, 0);
            La = __builtin_amdgcn_mfma_f32_32x32x16_bf16(ones8, pf[t][1], La, 0, 0, 0);
        }
        __builtin_amdgcn_s_setprio(0);

        __syncthreads();   // drains this wave's DMA (vmcnt 0) + all LDS reads
        buf ^= 1;
    }

    // epilogue: normalize by 1/l, O^T -> LDS f32 -> transposed coalesced
    // bf16 store direct to AO [B,T,H*64]. Reuse Ks/Vt region.
    const float rl = 1.0f / La[0];
    float* OT = (float*)SMEM;    // [64][132] f32 = 33792 B <= 36864 B
    #pragma unroll
    for (int hh = 0; hh < 2; ++hh)
        #pragma unroll
        for (int r = 0; r < 16; ++r) {
            int hd = hh * 32 + (r & 3) + ((r >> 2) << 3) + 4 * g;
            OT[hd * 132 + wave * 32 + l31] = Oa[hh][r] * rl;
        }
    __syncthreads();
    {
        const int q = tid >> 1, hc = (tid & 1) * 32;
        short tmp[32];
        #pragma unroll
        for (int i = 0; i < 32; ++i)
            tmp[i] = f2bf(OT[(hc + i) * 132 + q]);
        size_t ab = ((size_t)(b * TT + qbase + q) << 10) + h * 64 + hc;
        #pragma unroll
        for (int v = 0; v < 4; ++v)
            *(short8*)&AO[ab + v * 8] = *(short8*)&tmp[v * 8];
    }
}

// ---------------------------------------------------------------------------
extern "C" void kernel_launch(void* const* d_in, const int* in_sizes, int n_in,
                              void* d_out, int out_size, void* d_ws, size_t ws_size,
                              hipStream_t stream)
{
    char* ws = (char*)d_ws;
    const size_t XB  = (size_t)TM * TD * 2;   // 8 MiB bf16 x
    const size_t WB  = (size_t)TD * TD * 2;   // 2 MiB bf16 weight
    const size_t BUF = (size_t)TM * TD * 2;   // 8 MiB activation

    short* xb  = (short*)(ws + 256);
    short* Wqb = (short*)(ws + 256 + XB);
    short* Wkb = (short*)(ws + 256 + XB + WB);
    short* Wvb = (short*)(ws + 256 + XB + 2 * WB);
    short* Wob = (short*)(ws + 256 + XB + 3 * WB);
    char*  act = ws + 256 + XB + 4 * WB;
    short* Qb = (short*)(act);
    short* Kb = (short*)(act + BUF);
    short* Vb = (short*)(act + 2 * BUF);   // V^T [B,H,64,T]
    short* Ab = (short*)(act + 3 * BUF);

    dim3 blk(256);
    convert_all_kernel<<<dim3(512 + 4 * 128), blk, 0, stream>>>(
        d_in[0], d_in[1], d_in[2], d_in[3], d_in[4], xb, Wqb, Wkb, Wvb, Wob);
    qkv_gemm_kernel<<<dim3(TM / 128, TD / 128, 3), blk, 0, stream>>>(xb, Wqb, Wkb, Wvb, Qb, Kb, Vb);
    attn_fused_kernel<<<dim3(32, 16), blk, 0, stream>>>(Qb, Kb, Vb, Ab);
    out_gemm_kernel<<<dim3(TM / 64, TD / 128), blk, 0, stream>>>(
        Ab, Wob, d_out, (const unsigned short*)d_in[0]);
}

// Round 14
// 171.147 us; speedup vs baseline: 1.0621x; 1.0136x over previous
//
#include <hip/hip_runtime.h>
#include <hip/hip_bf16.h>

// Problem: B=2, T=2048, D=1024, H=16, HD=64.
// Runtime-detect fp32 vs bf16 inputs (inline, per-wave); canonicalize to bf16.
// convert_all -> qkv gemm (128x128, global_load_lds staging m97-style;
// Q,K:[B,H,T,64] via LDS-transpose epilogue; V:[B,H,64,T]; Q PRE-SCALED by
// log2(e)/sqrt(64)) -> SINGLE-PASS flash attention with 128-K TILES:
// Ks[2][128][64] + Vt[2][64][128] (64KB LDS, 2 blocks/CU), gload_lds dbuf,
// ONE barrier per 128-k tile (half the barrier count of the 64-k version;
// same proven syncthreads-dbuf semantics, parameter extension only).
// te = qt+1 tiles; diagonal tile masks per-subtile (skip t>wave). 32x32
// MFMA, swapped QK^T, P=exp2(S) (scale folded into Q), in-register pack via
// cvt_pk_bf16 + permlane32_swap, MFMA ones-row l, setprio, in-epilogue 1/l
// normalize + direct [B,T,H,64] store -> out gemm (64x128).

#define TB 2
#define TT 2048
#define TD 1024
#define TH 16
#define TM (TB * TT) // 4096

#define NEG_BIG (-1e30f)
#define SCALE_LOG2 0.18033688f  // (1/sqrt(64)) * log2(e), folded into Q
#define BF16_ONE ((short)0x3F80)

typedef __attribute__((ext_vector_type(8))) short short8;
typedef __attribute__((ext_vector_type(4))) float f32x4;
typedef __attribute__((ext_vector_type(16))) float f32x16;
typedef __attribute__((ext_vector_type(4))) unsigned short ushort4v;
typedef __attribute__((ext_vector_type(4))) unsigned int u32x4;

__device__ __forceinline__ short f2bf(float f) {
    __hip_bfloat16 h = __float2bfloat16(f);
    return __builtin_bit_cast(short, h);
}

__device__ __forceinline__ float bf2f(short u) {
    unsigned int x = ((unsigned int)(unsigned short)u) << 16;
    return __builtin_bit_cast(float, x);
}

__device__ __forceinline__ float fast_exp2(float x) {
#if __has_builtin(__builtin_amdgcn_exp2f)
    return __builtin_amdgcn_exp2f(x);
#else
    return exp2f(x);
#endif
}

__device__ __forceinline__ f32x16 zero16() {
    f32x16 v;
    #pragma unroll
    for (int i = 0; i < 16; ++i) v[i] = 0.f;
    return v;
}

// Async global->LDS DMA, 16 B/lane. LDS dest is wave-uniform base + lane*16;
// global src is per-lane (pre-swizzled). Completion counted by vmcnt; the
// compiler's s_waitcnt vmcnt(0) before s_barrier (__syncthreads) drains it.
__device__ __forceinline__ void gload_lds16(const short* g, short* l) {
    __builtin_amdgcn_global_load_lds(
        (const __attribute__((address_space(1))) unsigned int*)g,
        (__attribute__((address_space(3))) unsigned int*)l,
        16, 0, 0);
}

// Inline dtype detect: sample even u16s of x; uniform per wave.
__device__ __forceinline__ int detect_bf16(const unsigned short* xq) {
    int lane = threadIdx.x & 63;
    unsigned short u = xq[lane * 2];
    int e = (u >> 7) & 0xFF;
    int sane = ((e >= 100 && e <= 145) || u == 0) ? 1 : 0;
    unsigned long long b = __ballot(sane);
    return (__popcll(b) >= 48) ? 1 : 0; // 1 = bf16, 0 = fp32
}

// ---------------------------------------------------------------------------
// One dispatch converts x + 4 weights; 8192 elems/block.
// ---------------------------------------------------------------------------
__global__ __launch_bounds__(256) void convert_all_kernel(
    const void* __restrict__ x,  const void* __restrict__ wq,
    const void* __restrict__ wk, const void* __restrict__ wv,
    const void* __restrict__ wo,
    short* __restrict__ xb, short* __restrict__ wqb, short* __restrict__ wkb,
    short* __restrict__ wvb, short* __restrict__ wob)
{
    const int f = detect_bf16((const unsigned short*)x);
    int bid = blockIdx.x;
    const void* src; short* dst; int base;
    if (bid < 512) { src = x; dst = xb; base = bid; }
    else {
        int w = (bid - 512) >> 7, lb = (bid - 512) & 127;
        src = (w == 0) ? wq : (w == 1) ? wk : (w == 2) ? wv : wo;
        dst = (w == 0) ? wqb : (w == 1) ? wkb : (w == 2) ? wvb : wob;
        base = lb;
    }
    int i0 = base * 8192 + (int)threadIdx.x * 8;
    #pragma unroll
    for (int r = 0; r < 4; ++r) {
        int i = i0 + r * 2048;
        if (f) {
            *(short8*)(dst + i) = *(const short8*)((const short*)src + i);
        } else {
            const float* s = (const float*)src + i;
            short8 o;
            #pragma unroll
            for (int j = 0; j < 8; ++j) o[j] = f2bf(s[j]);
            *(short8*)(dst + i) = o;
        }
    }
}

// ---------------------------------------------------------------------------
// GEMM core, global_load_lds staging (m97 structure). C[m,n]=sum_k A[m,k]B[n,k].
// Tile: MROWS x 128, BK=64, K=1024. 4 waves (2x2). XOR chunk swizzle folded
// into the per-lane GLOBAL source address; LDS writes stay linear (lane*16B).
// ---------------------------------------------------------------------------
template<int MROWS>
__device__ __forceinline__ void gemm_core_lds(
    const short* __restrict__ A, const short* __restrict__ B,
    short* SM, int mbase, int nbase, f32x4 (*acc)[4])
{
    constexpr int TA = MROWS / 32;
    short* As = SM;
    short* Bs = SM + MROWS * 64;

    const int tid = threadIdx.x;
    const int wave = tid >> 6, lane = tid & 63;
    const int wm = wave >> 1, wn = wave & 1;
    const int lr = lane & 15;
    const int srow = lane >> 3, jcl = lane & 7;
    const int jc = (jcl ^ srow) * 8;   // (r&7)==srow for all staged rows

    #pragma unroll
    for (int a = 0; a < TA; ++a)
        #pragma unroll
        for (int b = 0; b < 4; ++b) acc[a][b] = (f32x4){0, 0, 0, 0};

    const short* aA[TA]; short* lA[TA];
    const short* aB[4];  short* lB[4];
    #pragma unroll
    for (int t = 0; t < TA; ++t) {
        int w = wave * TA + t;
        aA[t] = A + (size_t)(mbase + w * 8 + srow) * TD + jc;
        lA[t] = As + w * 512;
    }
    #pragma unroll
    for (int t = 0; t < 4; ++t) {
        int w = wave * 4 + t;
        aB[t] = B + (size_t)(nbase + w * 8 + srow) * TD + jc;
        lB[t] = Bs + w * 512;
    }

    // prologue: issue k0=0 tile
    #pragma unroll
    for (int t = 0; t < TA; ++t) gload_lds16(aA[t], lA[t]);
    #pragma unroll
    for (int t = 0; t < 4; ++t)  gload_lds16(aB[t], lB[t]);

    for (int k0 = 0; k0 < TD; k0 += 64) {
        __syncthreads();   // staged loads complete (vmcnt drained per-wave)
        #pragma unroll
        for (int kk = 0; kk < 64; kk += 32) {
            const int cc = (kk >> 3) + (lane >> 4);
            const int csw = (cc ^ (lr & 7)) << 3;
            short8 af[TA], bf[4];
            #pragma unroll
            for (int a = 0; a < TA; ++a)
                af[a] = *(const short8*)&As[(wm * (MROWS / 2) + a * 16 + lr) * 64 + csw];
            #pragma unroll
            for (int b = 0; b < 4; ++b)
                bf[b] = *(const short8*)&Bs[(wn * 64 + b * 16 + lr) * 64 + csw];
            #pragma unroll
            for (int a = 0; a < TA; ++a)
                #pragma unroll
                for (int b = 0; b < 4; ++b)
                    acc[a][b] = __builtin_amdgcn_mfma_f32_16x16x32_bf16(af[a], bf[b], acc[a][b], 0, 0, 0);
        }
        if (k0 + 64 < TD) {
            __syncthreads();   // all LDS reads done; safe to overwrite
            #pragma unroll
            for (int t = 0; t < TA; ++t) gload_lds16(aA[t] + k0 + 64, lA[t]);
            #pragma unroll
            for (int t = 0; t < 4; ++t)  gload_lds16(aB[t] + k0 + 64, lB[t]);
        }
    }
}

// ---------------------------------------------------------------------------
// QKV projection; 128x128 tiles, grid (32, 8, 3).
// Q,K out [B,H,T,64] via LDS-transpose epilogue; V out [B,H,64,T].
// Q is PRE-SCALED by SCALE_LOG2 so attention computes P = exp2(S) directly.
// ---------------------------------------------------------------------------
__global__ __launch_bounds__(256, 3) void qkv_gemm_kernel(
    const short* __restrict__ x,
    const short* __restrict__ Wq, const short* __restrict__ Wk,
    const short* __restrict__ Wv,
    short* __restrict__ Qo, short* __restrict__ Ko, short* __restrict__ Vo)
{
    const short* W = (blockIdx.z == 0) ? Wq : (blockIdx.z == 1) ? Wk : Wv;
    short* Out = (blockIdx.z == 0) ? Qo : (blockIdx.z == 1) ? Ko : Vo;
    const bool transposeV = (blockIdx.z == 2);
    const float qscale = (blockIdx.z == 0) ? SCALE_LOG2 : 1.0f;

    __shared__ __align__(16) short SM[128 * 64 * 2];

    const int mbase = blockIdx.x * 128, nbase = blockIdx.y * 128;
    f32x4 acc[4][4];
    gemm_core_lds<128>(x, W, SM, mbase, nbase, acc);

    const int tid = threadIdx.x;
    const int wave = tid >> 6, lane = tid & 63;
    const int wm = wave >> 1, wn = wave & 1;
    const int lr = lane & 15;
    const int g4 = (lane >> 4) * 4;

    if (transposeV) {
        #pragma unroll
        for (int a = 0; a < 4; ++a) {
            #pragma unroll
            for (int b = 0; b < 4; ++b) {
                int m0 = mbase + wm * 64 + a * 16 + g4;
                int n = nbase + wn * 64 + b * 16 + lr;
                int bb = m0 >> 11, t0 = m0 & (TT - 1);
                int h = n >> 6, hd = n & 63;
                ushort4v pk;
                #pragma unroll
                for (int i = 0; i < 4; ++i) pk[i] = (unsigned short)f2bf(acc[a][b][i]);
                *(ushort4v*)&Out[((size_t)(bb * TH + h) * 64 + hd) * TT + t0] = pk;
            }
        }
    } else {
        short* Cs = SM;
        #pragma unroll
        for (int p = 0; p < 2; ++p) {
            __syncthreads();
            if (wn == p) {
                #pragma unroll
                for (int a = 0; a < 4; ++a)
                    #pragma unroll
                    for (int b = 0; b < 4; ++b)
                        #pragma unroll
                        for (int i = 0; i < 4; ++i) {
                            int ml = wm * 64 + a * 16 + g4 + i;
                            int nl = b * 16 + lr;
                            Cs[ml * 72 + nl] = f2bf(acc[a][b][i] * qscale);
                        }
            }
            __syncthreads();
            int tl = tid >> 1, hc = (tid & 1) * 32;
            int h = (nbase >> 6) + p;
            int m = mbase + tl;
            int bb = m >> 11, t = m & (TT - 1);
            size_t base = (((size_t)(bb * TH + h) * TT + t) << 6) + hc;
            #pragma unroll
            for (int q = 0; q < 4; ++q)
                *(short8*)&Out[base + q * 8] = *(short8*)&Cs[tl * 72 + hc + q * 8];
        }
    }
}

// ---------------------------------------------------------------------------
// Output projection; 64x128 tiles, grid (64, 8).
// ---------------------------------------------------------------------------
__global__ __launch_bounds__(256, 3) void out_gemm_kernel(
    const short* __restrict__ A, const short* __restrict__ W,
    void* __restrict__ C, const unsigned short* __restrict__ xq)
{
    const int f = detect_bf16(xq);

    __shared__ __align__(16) short SM[64 * 64 + 128 * 64];

    const int mbase = blockIdx.x * 64, nbase = blockIdx.y * 128;
    f32x4 acc[2][4];
    gemm_core_lds<64>(A, W, SM, mbase, nbase, acc);

    const int tid = threadIdx.x;
    const int wave = tid >> 6, lane = tid & 63;
    const int wm = wave >> 1, wn = wave & 1;
    const int lr = lane & 15;
    const int g4 = (lane >> 4) * 4;

    #pragma unroll
    for (int a = 0; a < 2; ++a) {
        #pragma unroll
        for (int b = 0; b < 4; ++b) {
            #pragma unroll
            for (int i = 0; i < 4; ++i) {
                int m = mbase + wm * 32 + a * 16 + g4 + i;
                int n = nbase + wn * 64 + b * 16 + lr;
                if (f) ((short*)C)[(size_t)m * TD + n] = f2bf(acc[a][b][i]);
                else   ((float*)C)[(size_t)m * TD + n] = acc[a][b][i];
            }
        }
    }
}

// ---------------------------------------------------------------------------
// SINGLE-PASS flash attention, 128-K TILES. 32x32 MFMA, swapped QK^T
// (S^T = K Q^T), softmax in registers: P = exp2(S) (scale pre-folded into
// Q). 128 q-rows/block (4 waves x 32 q-rows). K/V staged via global_load_lds
// into Ks[2][128][64] (8-chunk XOR ^(row&7)) and Vt[2][64][128] (16-chunk
// XOR ^(row&15)), both sides of each involution; dbuf, staging at loop TOP,
// ONE barrier per 128-k tile. te = qt+1 tiles; diagonal tile (it==qt) skips
// subtiles t>wave and masks t==wave per-lane. grid (32 bh, 16 y);
// qt=(y<8)?15-y:y-8 (RR pairs y,y+8 sum 15 -> balanced CU load).
// Epilogue: 1/l normalize, LDS transpose, direct [B,T,H,64] store.
// ---------------------------------------------------------------------------
__global__ __launch_bounds__(256, 2) void attn_fused_kernel(
    const short* __restrict__ Q, const short* __restrict__ K,
    const short* __restrict__ V, short* __restrict__ AO)
{
    const int bh = blockIdx.x;
    const int y = blockIdx.y;
    const int qt = (y < 8) ? (15 - y) : (y - 8);   // heavy first; pairs sum 15
    const int te = qt + 1;                         // 128-k tiles [0, te)

    const int qbase = qt * 128;
    const int b = bh >> 4, h = bh & 15;
    const short* Qp = Q + (size_t)bh * TT * 64;
    const short* Kp = K + (size_t)bh * TT * 64;
    const short* Vp = V + (size_t)bh * 64 * TT;   // V^T: [64][TT]

    __shared__ __align__(16) short SMEM[32768];   // 64KB: Ks[2][128][64] | Vt[2][64][128]
    short* KsL = SMEM;            // buf stride 8192 shorts
    short* VtL = SMEM + 16384;    // buf stride 8192 shorts

    const int tid = threadIdx.x;
    const int wave = tid >> 6, lane = tid & 63;
    const int l31 = lane & 31, g = lane >> 5;

    // Q fragments (B-operand): lane holds q-row qrow, 64 hd in 4 chunks
    const int qrow0 = qbase + wave * 32;      // wave's min q (uniform)
    const int qrow = qrow0 + l31;             // this lane's q row
    short8 qf[4];
    #pragma unroll
    for (int c = 0; c < 4; ++c)
        qf[c] = *(const short8*)&Qp[(size_t)qrow * 64 + c * 16 + g * 8];

    short8 ones8;
    #pragma unroll
    for (int i = 0; i < 8; ++i) ones8[i] = BF16_ONE;

    f32x16 Oa[2];                // O^T accum: [hd-tile][ (hd-row, q) frag ]
    Oa[0] = zero16(); Oa[1] = zero16();
    f32x16 La = zero16();        // l (all rows identical = l[q=l31])

    // stage 128-k tile `it` into buffer bufv (8 gload_lds per thread).
    // K: rows kt..kt+127 x 64 hd, 8 chunks/row, src chunk ^= row&7.
    // V: 64 hd-rows x k kt..kt+127, 16 chunks/row, src chunk ^= row&15.
    // LDS dests are wave-uniform bases; HW adds lane*16B (linear layout).
    auto stage = [&](int it, int bufv) {
        const int kt = it * 128;
        short* kd = KsL + bufv * 8192;
        short* vd = VtL + bufv * 8192;
        #pragma unroll
        for (int r = 0; r < 4; ++r) {
            int krow = r * 32 + (tid >> 3);        // 0..127
            gload_lds16(&Kp[(size_t)(kt + krow) * 64 + (((tid & 7) ^ (krow & 7)) * 8)],
                        kd + (r * 32 + wave * 8) * 64);
        }
        #pragma unroll
        for (int r = 0; r < 4; ++r) {
            int vrow = r * 16 + (tid >> 4);        // 0..63
            gload_lds16(&Vp[(size_t)vrow * TT + kt + (((tid & 15) ^ (vrow & 15)) * 8)],
                        vd + (r * 16 + wave * 4) * 128);
        }
    };

    // prologue: stage first tile into buf 0 (drained by first barrier)
    stage(0, 0);
    __syncthreads();

    int buf = 0;
    for (int it = 0; it < te; ++it) {
        const bool more = (it + 1) < te;
        // issue next tile's DMA into the alternate buffer NOW: it flies under
        // this tile's compute; end-of-tile barrier's vmcnt drain covers it.
        if (more) stage(it + 1, buf ^ 1);

        const int kt = it * 128;
        const int kb = buf * 8192;
        const bool last = (it == qt);

        #pragma unroll
        for (int t = 0; t < 4; ++t) {
            if (last && t > wave) continue;   // fully masked (wave-uniform)
            const int kb32 = kt + t * 32;

            // ---- QK^T: S(32k x 32q) over hd=64 ----
            f32x16 S = zero16();
            __builtin_amdgcn_s_setprio(1);
            #pragma unroll
            for (int c = 0; c < 4; ++c) {
                short8 kf = *(const short8*)&KsL[kb + (t * 32 + l31) * 64 + (((2 * c + g) ^ (l31 & 7)) * 8)];
                S = __builtin_amdgcn_mfma_f32_32x32x16_bf16(kf, qf[c], S, 0, 0, 0);
            }
            __builtin_amdgcn_s_setprio(0);

            // ---- P = exp2(S); mask only diagonal subtile (t==wave, last) ----
            if (last && t == wave) {
                #pragma unroll
                for (int r = 0; r < 16; ++r) {
                    int kglob = kb32 + (r & 3) + ((r >> 2) << 3) + 4 * g;
                    S[r] = fast_exp2(kglob > qrow ? NEG_BIG : S[r]);
                }
            } else {
                #pragma unroll
                for (int r = 0; r < 16; ++r)
                    S[r] = fast_exp2(S[r]);
            }

            // ---- pack to bf16 B-fragments in-register (T12) ----
            unsigned int w_[8];
            #pragma unroll
            for (int j = 0; j < 2; ++j) {
                unsigned int a, bq;
                asm("v_cvt_pk_bf16_f32 %0, %1, %2" : "=v"(a) : "v"(S[2 * j]), "v"(S[2 * j + 1]));
                asm("v_cvt_pk_bf16_f32 %0, %1, %2" : "=v"(bq) : "v"(S[2 * j + 4]), "v"(S[2 * j + 5]));
                asm("v_permlane32_swap_b32 %0, %1" : "+v"(a), "+v"(bq));
                w_[j] = a; w_[j + 2] = bq;
                unsigned int a2, b2;
                asm("v_cvt_pk_bf16_f32 %0, %1, %2" : "=v"(a2) : "v"(S[8 + 2 * j]), "v"(S[9 + 2 * j]));
                asm("v_cvt_pk_bf16_f32 %0, %1, %2" : "=v"(b2) : "v"(S[12 + 2 * j]), "v"(S[13 + 2 * j]));
                asm("v_permlane32_swap_b32 %0, %1" : "+v"(a2), "+v"(b2));
                w_[4 + j] = a2; w_[6 + j] = b2;
            }
            u32x4 u0 = {w_[0], w_[1], w_[2], w_[3]};
            u32x4 u1 = {w_[4], w_[5], w_[6], w_[7]};
            short8 pf0 = __builtin_bit_cast(short8, u0);  // k [kb32, kb32+16)
            short8 pf1 = __builtin_bit_cast(short8, u1);  // k [kb32+16, +32)

            // ---- PV + l ----
            __builtin_amdgcn_s_setprio(1);
            #pragma unroll
            for (int hh = 0; hh < 2; ++hh) {
                int vr = hh * 32 + l31;
                int lc0 = 4 * t + g;       // k chunk for pf0 half g
                short8 vf0 = *(const short8*)&VtL[kb + vr * 128 + ((lc0 ^ (vr & 15)) * 8)];
                Oa[hh] = __builtin_amdgcn_mfma_f32_32x32x16_bf16(vf0, pf0, Oa[hh], 0, 0, 0);
                int lc1 = 4 * t + 2 + g;   // k chunk for pf1 half g
                short8 vf1 = *(const short8*)&VtL[kb + vr * 128 + ((lc1 ^ (vr & 15)) * 8)];
                Oa[hh] = __builtin_amdgcn_mfma_f32_32x32x16_bf16(vf1, pf1, Oa[hh], 0, 0, 0);
            }
            La = __builtin_amdgcn_mfma_f32_32x32x16_bf16(ones8, pf0, La, 0, 0, 0);
            La = __builtin_amdgcn_mfma_f32_32x32x16_bf16(ones8, pf1, La, 0, 0, 0);
            __builtin_amdgcn_s_setprio(0);
        }

        __syncthreads();   // drains this wave's DMA (vmcnt 0) + all LDS reads
        buf ^= 1;
    }

    // epilogue: normalize by 1/l, O^T -> LDS f32 -> transposed coalesced
    // bf16 store direct to AO [B,T,H*64]. Reuse Ks/Vt region (last barrier
    // of the loop already passed).
    const float rl = 1.0f / La[0];
    float* OT = (float*)SMEM;    // [64][132] f32 = 33792 B <= 65536 B
    #pragma unroll
    for (int hh = 0; hh < 2; ++hh)
        #pragma unroll
        for (int r = 0; r < 16; ++r) {
            int hd = hh * 32 + (r & 3) + ((r >> 2) << 3) + 4 * g;
            OT[hd * 132 + wave * 32 + l31] = Oa[hh][r] * rl;
        }
    __syncthreads();
    {
        const int q = tid >> 1, hc = (tid & 1) * 32;
        short tmp[32];
        #pragma unroll
        for (int i = 0; i < 32; ++i)
            tmp[i] = f2bf(OT[(hc + i) * 132 + q]);
        size_t ab = ((size_t)(b * TT + qbase + q) << 10) + h * 64 + hc;
        #pragma unroll
        for (int v = 0; v < 4; ++v)
            *(short8*)&AO[ab + v * 8] = *(short8*)&tmp[v * 8];
    }
}

// ---------------------------------------------------------------------------
extern "C" void kernel_launch(void* const* d_in, const int* in_sizes, int n_in,
                              void* d_out, int out_size, void* d_ws, size_t ws_size,
                              hipStream_t stream)
{
    char* ws = (char*)d_ws;
    const size_t XB  = (size_t)TM * TD * 2;   // 8 MiB bf16 x
    const size_t WB  = (size_t)TD * TD * 2;   // 2 MiB bf16 weight
    const size_t BUF = (size_t)TM * TD * 2;   // 8 MiB activation

    short* xb  = (short*)(ws + 256);
    short* Wqb = (short*)(ws + 256 + XB);
    short* Wkb = (short*)(ws + 256 + XB + WB);
    short* Wvb = (short*)(ws + 256 + XB + 2 * WB);
    short* Wob = (short*)(ws + 256 + XB + 3 * WB);
    char*  act = ws + 256 + XB + 4 * WB;
    short* Qb = (short*)(act);
    short* Kb = (short*)(act + BUF);
    short* Vb = (short*)(act + 2 * BUF);   // V^T [B,H,64,T]
    short* Ab = (short*)(act + 3 * BUF);

    dim3 blk(256);
    convert_all_kernel<<<dim3(512 + 4 * 128), blk, 0, stream>>>(
        d_in[0], d_in[1], d_in[2], d_in[3], d_in[4], xb, Wqb, Wkb, Wvb, Wob);
    qkv_gemm_kernel<<<dim3(TM / 128, TD / 128, 3), blk, 0, stream>>>(xb, Wqb, Wkb, Wvb, Qb, Kb, Vb);
    attn_fused_kernel<<<dim3(32, 16), blk, 0, stream>>>(Qb, Kb, Vb, Ab);
    out_gemm_kernel<<<dim3(TM / 64, TD / 128), blk, 0, stream>>>(
        Ab, Wob, d_out, (const unsigned short*)d_in[0]);
}